// Round 2
// baseline (1768.125 us; speedup 1.0000x reference)
//
#include <hip/hip_runtime.h>
#include <hip/hip_bf16.h>
#include <math.h>

#define N_NODES 100000
#define N_EDGES 1600000
#define N_GRAPHS 512
#define IN_DIM 1024
#define HID 128
#define HEADS 4
#define CH 32
#define NEG_SLOPE 0.2f

__device__ __forceinline__ float leaky(float x) {
    return x >= 0.f ? x : NEG_SLOPE * x;
}

// ---------------- GEMM: C[M][128] = act(A[M][K] @ W[K][128] (+ bias)) ----------------
// block 256 threads, tile 64 rows x 128 cols, K-tile 32. ACT: 0=none, 1=exact GELU.
template <int ACT>
__global__ __launch_bounds__(256) void gemm_act(const float* __restrict__ A,
                                                const float* __restrict__ W,
                                                const float* __restrict__ bias,
                                                float* __restrict__ C, int M, int K) {
    __shared__ float sA[64][32];
    __shared__ float sW[32][128];
    const int tid = threadIdx.x;
    const int tx = tid & 31;   // col group: cols tx*4 .. tx*4+3
    const int ty = tid >> 5;   // row group: rows ty*8 .. ty*8+7
    const int row0 = blockIdx.x * 64;

    float acc[8][4];
#pragma unroll
    for (int i = 0; i < 8; i++)
#pragma unroll
        for (int j = 0; j < 4; j++) acc[i][j] = 0.f;

    for (int k0 = 0; k0 < K; k0 += 32) {
        // A tile: 64 rows x 32 k = 512 float4, 2 per thread
#pragma unroll
        for (int it = 0; it < 2; it++) {
            int idx = tid + it * 256;  // 0..511
            int r = idx >> 3;
            int s = idx & 7;
            int gr = row0 + r;
            float4 v = make_float4(0.f, 0.f, 0.f, 0.f);
            if (gr < M) v = *reinterpret_cast<const float4*>(&A[(size_t)gr * K + k0 + s * 4]);
            *reinterpret_cast<float4*>(&sA[r][s * 4]) = v;
        }
        // W tile: 32 x 128 = 1024 float4, 4 per thread
#pragma unroll
        for (int it = 0; it < 4; it++) {
            int idx = tid + it * 256;  // 0..1023
            int r = idx >> 5;
            int cs = idx & 31;
            float4 v = *reinterpret_cast<const float4*>(&W[(size_t)(k0 + r) * HID + cs * 4]);
            *reinterpret_cast<float4*>(&sW[r][cs * 4]) = v;
        }
        __syncthreads();
#pragma unroll
        for (int kk = 0; kk < 32; kk++) {
            float4 w = *reinterpret_cast<const float4*>(&sW[kk][tx * 4]);
#pragma unroll
            for (int i = 0; i < 8; i++) {
                float a = sA[ty * 8 + i][kk];
                acc[i][0] += a * w.x;
                acc[i][1] += a * w.y;
                acc[i][2] += a * w.z;
                acc[i][3] += a * w.w;
            }
        }
        __syncthreads();
    }
#pragma unroll
    for (int i = 0; i < 8; i++) {
        int gr = row0 + ty * 8 + i;
        if (gr >= M) continue;
        float4 o;
        float* po = &o.x;
#pragma unroll
        for (int j = 0; j < 4; j++) {
            float v = acc[i][j];
            int c = tx * 4 + j;
            if (bias) v += bias[c];
            if (ACT == 1) v = 0.5f * v * (1.f + erff(v * 0.70710678118654752f));
            po[j] = v;
        }
        *reinterpret_cast<float4*>(&C[(size_t)gr * HID + tx * 4]) = o;
    }
}

// ---------------- attention logits: As[n,h] = h[n,h,:]·a_src[h,:] ----------------
__global__ __launch_bounds__(256) void alpha_kernel(const float* __restrict__ H,
                                                    const float* __restrict__ a_src,
                                                    const float* __restrict__ a_dst,
                                                    float* __restrict__ As,
                                                    float* __restrict__ Ad) {
    __shared__ float ss[HID], sd[HID];
    int tid = threadIdx.x;
    if (tid < HID) {
        ss[tid] = a_src[tid];
        sd[tid] = a_dst[tid];
    }
    __syncthreads();
    int gid = blockIdx.x * 256 + tid;
    if (gid >= N_NODES * HEADS) return;
    int n = gid >> 2;
    int head = gid & 3;
    const float* hp = &H[(size_t)n * HID + head * CH];
    const float* sp = &ss[head * CH];
    const float* dp = &sd[head * CH];
    float s = 0.f, d = 0.f;
#pragma unroll
    for (int k = 0; k < CH; k += 4) {
        float4 v = *reinterpret_cast<const float4*>(&hp[k]);
        s += v.x * sp[k] + v.y * sp[k + 1] + v.z * sp[k + 2] + v.w * sp[k + 3];
        d += v.x * dp[k] + v.y * dp[k + 1] + v.z * dp[k + 2] + v.w * dp[k + 3];
    }
    As[gid] = s;
    Ad[gid] = d;
}

// ---------------- CSR build ----------------
__global__ void count_kernel(const int* __restrict__ ei, int* __restrict__ counts) {
    int e = blockIdx.x * 256 + threadIdx.x;
    if (e < N_EDGES) atomicAdd(&counts[ei[N_EDGES + e]], 1);
}

// per-block exclusive scan over 1024 elements (256 threads x 4)
__global__ void scan1(const int* __restrict__ counts, int* __restrict__ rowptr,
                      int* __restrict__ bsums) {
    __shared__ int sdata[256];
    int tid = threadIdx.x;
    int base = blockIdx.x * 1024 + tid * 4;
    int v[4];
#pragma unroll
    for (int i = 0; i < 4; i++) {
        int idx = base + i;
        v[i] = (idx < N_NODES) ? counts[idx] : 0;
    }
    int t = v[0] + v[1] + v[2] + v[3];
    sdata[tid] = t;
    __syncthreads();
    for (int off = 1; off < 256; off <<= 1) {
        int x = (tid >= off) ? sdata[tid - off] : 0;
        __syncthreads();
        sdata[tid] += x;
        __syncthreads();
    }
    int run = sdata[tid] - t;  // exclusive prefix of this thread's chunk
#pragma unroll
    for (int i = 0; i < 4; i++) {
        int idx = base + i;
        if (idx < N_NODES) rowptr[idx] = run;
        run += v[i];
    }
    if (tid == 255) bsums[blockIdx.x] = sdata[255];
}

__global__ void scan2(int* __restrict__ bsums, int nb, int* __restrict__ total) {
    __shared__ int s[128];
    int tid = threadIdx.x;
    int v = (tid < nb) ? bsums[tid] : 0;
    s[tid] = v;
    __syncthreads();
    for (int off = 1; off < 128; off <<= 1) {
        int x = (tid >= off) ? s[tid - off] : 0;
        __syncthreads();
        s[tid] += x;
        __syncthreads();
    }
    if (tid < nb) bsums[tid] = s[tid] - v;  // exclusive
    if (tid == 127) *total = s[127];        // rowptr[N] = E
}

__global__ void scan3(int* __restrict__ rowptr, const int* __restrict__ bsums,
                      int* __restrict__ pos) {
    int b = blockIdx.x;
    int base = b * 1024 + threadIdx.x * 4;
    int add = bsums[b];
#pragma unroll
    for (int i = 0; i < 4; i++) {
        int idx = base + i;
        if (idx < N_NODES) {
            int r = rowptr[idx] + add;
            rowptr[idx] = r;
            pos[idx] = r;
        }
    }
}

__global__ void fill_kernel(const int* __restrict__ ei, int* __restrict__ pos,
                            int* __restrict__ csr_src) {
    int e = blockIdx.x * 256 + threadIdx.x;
    if (e < N_EDGES) {
        int s = ei[e];
        int d = ei[N_EDGES + e];
        int slot = atomicAdd(&pos[d], 1);
        csr_src[slot] = s;
    }
}

// ---------------- GAT aggregation: one wave per dst node ----------------
// lane -> channel pair (2*lane, 2*lane+1); head = lane>>4. Self-loop implicit.
__global__ __launch_bounds__(256) void gat_aggregate(
    const float* __restrict__ H, const float* __restrict__ As,
    const float* __restrict__ Ad, const int* __restrict__ rowptr,
    const int* __restrict__ csr_src, const float* __restrict__ bg,
    float* __restrict__ out) {
    int wave = threadIdx.x >> 6;
    int lane = threadIdx.x & 63;
    int dst = blockIdx.x * 4 + wave;
    if (dst >= N_NODES) return;
    int head = lane >> 4;

    float ad = Ad[dst * HEADS + head];
    float e_self = leaky(As[dst * HEADS + head] + ad);
    int e0 = rowptr[dst], e1 = rowptr[dst + 1];

    // pass A: per-head max (every lane of a head computes it redundantly)
    float m = e_self;
    for (int e = e0; e < e1; e++) {
        int s = csr_src[e];
        m = fmaxf(m, leaky(As[s * HEADS + head] + ad));
    }

    // pass B: softmax-weighted sum
    float denom = 0.f, acc0 = 0.f, acc1 = 0.f;
    {
        float ex = __expf(e_self - m);
        denom += ex;
        float2 hv = *reinterpret_cast<const float2*>(&H[(size_t)dst * HID + lane * 2]);
        acc0 += ex * hv.x;
        acc1 += ex * hv.y;
    }
    for (int e = e0; e < e1; e++) {
        int s = csr_src[e];
        float ex = __expf(leaky(As[s * HEADS + head] + ad) - m);
        denom += ex;
        float2 hv = *reinterpret_cast<const float2*>(&H[(size_t)s * HID + lane * 2]);
        acc0 += ex * hv.x;
        acc1 += ex * hv.y;
    }
    int c = lane * 2;
    float rd = 1.f / denom;
    float o0 = fmaxf(acc0 * rd + bg[c], 0.f);
    float o1 = fmaxf(acc1 * rd + bg[c + 1], 0.f);
    *reinterpret_cast<float2*>(&out[(size_t)dst * HID + c]) = make_float2(o0, o1);
}

// ---------------- global_add_pool (batch is sorted) ----------------
__global__ __launch_bounds__(128) void pool_kernel(const float* __restrict__ X,
                                                   const int* __restrict__ batch,
                                                   float* __restrict__ out) {
    int tid = threadIdx.x;  // channel
    int n0 = blockIdx.x * 512;
    int n1 = n0 + 512;
    if (n1 > N_NODES) n1 = N_NODES;
    int cur = batch[n0];
    float acc = 0.f;
    for (int n = n0; n < n1; n++) {
        int g = batch[n];
        float v = X[(size_t)n * HID + tid];
        if (g != cur) {
            atomicAdd(&out[cur * HID + tid], acc);
            acc = 0.f;
            cur = g;
        }
        acc += v;
    }
    atomicAdd(&out[cur * HID + tid], acc);
}

extern "C" void kernel_launch(void* const* d_in, const int* in_sizes, int n_in,
                              void* d_out, int out_size, void* d_ws, size_t ws_size,
                              hipStream_t stream) {
    (void)in_sizes; (void)n_in; (void)out_size; (void)ws_size;
    const float* nf    = (const float*)d_in[0];
    const int*   ei    = (const int*)d_in[1];
    const int*   batch = (const int*)d_in[2];
    const float* W1    = (const float*)d_in[3];
    const float* b1    = (const float*)d_in[4];
    const float* Wg    = (const float*)d_in[5];
    const float* a_src = (const float*)d_in[6];
    const float* a_dst = (const float*)d_in[7];
    const float* bg    = (const float*)d_in[8];
    float* out = (float*)d_out;

    char* ws = (char*)d_ws;
    size_t off = 0;
    auto alloc = [&](size_t bytes) -> char* {
        char* p = ws + off;
        off += (bytes + 255) & ~(size_t)255;
        return p;
    };
    const size_t SZX = (size_t)N_NODES * HID * sizeof(float);
    float* xA     = (float*)alloc(SZX);
    float* xB     = (float*)alloc(SZX);
    float* Hbuf   = (float*)alloc(SZX);
    float* As     = (float*)alloc((size_t)N_NODES * HEADS * sizeof(float));
    float* Ad     = (float*)alloc((size_t)N_NODES * HEADS * sizeof(float));
    int*   counts = (int*)alloc((size_t)N_NODES * sizeof(int));
    int*   rowptr = (int*)alloc((size_t)(N_NODES + 1) * sizeof(int));
    int*   pos    = (int*)alloc((size_t)N_NODES * sizeof(int));
    int*   bsums  = (int*)alloc(512);
    int*   csr    = (int*)alloc((size_t)N_EDGES * sizeof(int));

    hipMemsetAsync(counts, 0, (size_t)N_NODES * sizeof(int), stream);
    hipMemsetAsync(out, 0, (size_t)N_GRAPHS * HID * sizeof(float), stream);

    // featurizer: x = gelu(nf @ W1 + b1)
    gemm_act<1><<<(N_NODES + 63) / 64, 256, 0, stream>>>(nf, W1, b1, xA, N_NODES, IN_DIM);

    // CSR by dst (self-loops implicit)
    count_kernel<<<N_EDGES / 256, 256, 0, stream>>>(ei, counts);
    const int NSB = (N_NODES + 1023) / 1024;  // 98
    scan1<<<NSB, 256, 0, stream>>>(counts, rowptr, bsums);
    scan2<<<1, 128, 0, stream>>>(bsums, NSB, rowptr + N_NODES);
    scan3<<<NSB, 256, 0, stream>>>(rowptr, bsums, pos);
    fill_kernel<<<N_EDGES / 256, 256, 0, stream>>>(ei, pos, csr);

    const float* x = xA;
    float* nx = xB;
    for (int l = 0; l < 2; l++) {
        gemm_act<0><<<(N_NODES + 63) / 64, 256, 0, stream>>>(x, Wg + (size_t)l * HID * HID,
                                                             nullptr, Hbuf, N_NODES, HID);
        alpha_kernel<<<(N_NODES * HEADS + 255) / 256, 256, 0, stream>>>(
            Hbuf, a_src + (size_t)l * HEADS * CH, a_dst + (size_t)l * HEADS * CH, As, Ad);
        gat_aggregate<<<N_NODES / 4, 256, 0, stream>>>(Hbuf, As, Ad, rowptr, csr,
                                                       bg + (size_t)l * HID, nx);
        float* t = (float*)x;
        x = nx;
        nx = t;
    }
    pool_kernel<<<(N_NODES + 511) / 512, 128, 0, stream>>>(x, batch, out);
}

// Round 3
// 1322.239 us; speedup vs baseline: 1.3372x; 1.3372x over previous
//
#include <hip/hip_runtime.h>
#include <hip/hip_bf16.h>
#include <math.h>

#define N_NODES 100000
#define N_EDGES 1600000
#define N_GRAPHS 512
#define IN_DIM 1024
#define HID 128
#define HEADS 4
#define CH 32
#define NEG_SLOPE 0.2f

typedef __attribute__((ext_vector_type(8))) short short8v;  // 8 bf16 (4 VGPRs)
typedef __attribute__((ext_vector_type(4))) short short4v;
typedef __attribute__((ext_vector_type(4))) float f32x4;

__device__ __forceinline__ float leaky(float x) {
    return x >= 0.f ? x : NEG_SLOPE * x;
}

// fp32 -> bf16 round-to-nearest-even
__device__ __forceinline__ short f2bf(float f) {
    unsigned u = __builtin_bit_cast(unsigned, f);
    unsigned r = u + 0x7FFFu + ((u >> 16) & 1u);
    return (short)(r >> 16);
}

// ---------------- prep: WT[n][k] = bf16(W1[k][n]), n<128, k<1024 ----------------
__global__ __launch_bounds__(256) void prep_wt(const float* __restrict__ W1,
                                               short* __restrict__ WT) {
    int n = blockIdx.x;       // 0..127
    int t = threadIdx.x;      // 0..255, each 4 k's
    short4v o;
#pragma unroll
    for (int j = 0; j < 4; j++) {
        int k = t * 4 + j;
        o[j] = f2bf(W1[(size_t)k * HID + n]);
    }
    *reinterpret_cast<short4v*>(&WT[(size_t)n * IN_DIM + t * 4]) = o;
}

// ---------------- GEMM1 (bf16 MFMA): C = gelu(A[M][1024] @ W + b) ----------------
// block 256 (4 waves), tile 64 rows x 128 cols, BK=64. A fp32->bf16 on the fly.
// LDS XOR-swizzle: col-block ^ (row & 7)  (T2; store & read sides identical).
__global__ __launch_bounds__(256) void gemm1_mfma(const float* __restrict__ A,
                                                  const short* __restrict__ WT,
                                                  const float* __restrict__ bias,
                                                  float* __restrict__ C, int M) {
    __shared__ short sA[64][64];
    __shared__ short sB[128][64];
    const int tid = threadIdx.x;
    const int lane = tid & 63;
    const int wave = tid >> 6;
    const int row0 = blockIdx.x * 64;

    // staging maps
    const int ar = tid >> 2;          // A row 0..63
    const int acb = (tid & 3) * 2;    // A col-block base (2 blocks of 8)
    const int bn = tid >> 1;          // B row (n) 0..127
    const int bcb = (tid & 1) * 4;    // B col-block base (4 blocks of 8)
    // fragment maps
    const int r = lane & 15;
    const int q = lane >> 4;

    f32x4 acc[8];
#pragma unroll
    for (int i = 0; i < 8; i++) acc[i] = (f32x4){0.f, 0.f, 0.f, 0.f};

    const bool arow_ok = (row0 + ar) < M;
    const float* aptr = A + (size_t)(row0 + ar) * IN_DIM + acb * 8;
    const short* wptr = WT + (size_t)bn * IN_DIM + bcb * 8;

    for (int k0 = 0; k0 < IN_DIM; k0 += 64) {
        // stage A: 16 floats/thread -> 2 bf16x8 LDS chunks
        {
            float4 f0, f1, f2, f3;
            if (arow_ok) {
                const float4* p = reinterpret_cast<const float4*>(aptr + k0);
                f0 = p[0]; f1 = p[1]; f2 = p[2]; f3 = p[3];
            } else {
                f0 = f1 = f2 = f3 = make_float4(0.f, 0.f, 0.f, 0.f);
            }
            short8v c0, c1;
            c0[0] = f2bf(f0.x); c0[1] = f2bf(f0.y); c0[2] = f2bf(f0.z); c0[3] = f2bf(f0.w);
            c0[4] = f2bf(f1.x); c0[5] = f2bf(f1.y); c0[6] = f2bf(f1.z); c0[7] = f2bf(f1.w);
            c1[0] = f2bf(f2.x); c1[1] = f2bf(f2.y); c1[2] = f2bf(f2.z); c1[3] = f2bf(f2.w);
            c1[4] = f2bf(f3.x); c1[5] = f2bf(f3.y); c1[6] = f2bf(f3.z); c1[7] = f2bf(f3.w);
            *reinterpret_cast<short8v*>(&sA[ar][((acb) ^ (ar & 7)) * 8]) = c0;
            *reinterpret_cast<short8v*>(&sA[ar][((acb + 1) ^ (ar & 7)) * 8]) = c1;
        }
        // stage B: 32 bf16/thread -> 4 chunks
        {
            const short8v* p = reinterpret_cast<const short8v*>(wptr + k0);
            short8v b0 = p[0], b1 = p[1], b2 = p[2], b3 = p[3];
            *reinterpret_cast<short8v*>(&sB[bn][((bcb) ^ (bn & 7)) * 8]) = b0;
            *reinterpret_cast<short8v*>(&sB[bn][((bcb + 1) ^ (bn & 7)) * 8]) = b1;
            *reinterpret_cast<short8v*>(&sB[bn][((bcb + 2) ^ (bn & 7)) * 8]) = b2;
            *reinterpret_cast<short8v*>(&sB[bn][((bcb + 3) ^ (bn & 7)) * 8]) = b3;
        }
        __syncthreads();
#pragma unroll
        for (int kk = 0; kk < 2; kk++) {
            const int sc = ((kk * 4 + q) ^ (r & 7)) * 8;
            short8v a = *reinterpret_cast<const short8v*>(&sA[wave * 16 + r][sc]);
#pragma unroll
            for (int ns = 0; ns < 8; ns++) {
                short8v b = *reinterpret_cast<const short8v*>(&sB[ns * 16 + r][sc]);
                acc[ns] = __builtin_amdgcn_mfma_f32_16x16x32_bf16(a, b, acc[ns], 0, 0, 0);
            }
        }
        __syncthreads();
    }
    // epilogue: C/D layout col=lane&15, row=(lane>>4)*4+reg
#pragma unroll
    for (int ns = 0; ns < 8; ns++) {
        const int col = ns * 16 + r;
        const float bv = bias[col];
#pragma unroll
        for (int j = 0; j < 4; j++) {
            int grow = row0 + wave * 16 + q * 4 + j;
            if (grow < M) {
                float v = acc[ns][j] + bv;
                v = 0.5f * v * (1.f + erff(v * 0.70710678118654752f));
                C[(size_t)grow * HID + col] = v;
            }
        }
    }
}

// ---------------- fp32 GEMM (layer proj, K=128): C = A @ W ----------------
template <int ACT>
__global__ __launch_bounds__(256) void gemm_act(const float* __restrict__ A,
                                                const float* __restrict__ W,
                                                const float* __restrict__ bias,
                                                float* __restrict__ C, int M, int K) {
    __shared__ float sA[64][32];
    __shared__ float sW[32][128];
    const int tid = threadIdx.x;
    const int tx = tid & 31;
    const int ty = tid >> 5;
    const int row0 = blockIdx.x * 64;

    float acc[8][4];
#pragma unroll
    for (int i = 0; i < 8; i++)
#pragma unroll
        for (int j = 0; j < 4; j++) acc[i][j] = 0.f;

    for (int k0 = 0; k0 < K; k0 += 32) {
#pragma unroll
        for (int it = 0; it < 2; it++) {
            int idx = tid + it * 256;
            int rr = idx >> 3;
            int s = idx & 7;
            int gr = row0 + rr;
            float4 v = make_float4(0.f, 0.f, 0.f, 0.f);
            if (gr < M) v = *reinterpret_cast<const float4*>(&A[(size_t)gr * K + k0 + s * 4]);
            *reinterpret_cast<float4*>(&sA[rr][s * 4]) = v;
        }
#pragma unroll
        for (int it = 0; it < 4; it++) {
            int idx = tid + it * 256;
            int rr = idx >> 5;
            int cs = idx & 31;
            float4 v = *reinterpret_cast<const float4*>(&W[(size_t)(k0 + rr) * HID + cs * 4]);
            *reinterpret_cast<float4*>(&sW[rr][cs * 4]) = v;
        }
        __syncthreads();
#pragma unroll
        for (int kk = 0; kk < 32; kk++) {
            float4 w = *reinterpret_cast<const float4*>(&sW[kk][tx * 4]);
#pragma unroll
            for (int i = 0; i < 8; i++) {
                float a = sA[ty * 8 + i][kk];
                acc[i][0] += a * w.x;
                acc[i][1] += a * w.y;
                acc[i][2] += a * w.z;
                acc[i][3] += a * w.w;
            }
        }
        __syncthreads();
    }
#pragma unroll
    for (int i = 0; i < 8; i++) {
        int gr = row0 + ty * 8 + i;
        if (gr >= M) continue;
        float4 o;
        float* po = &o.x;
#pragma unroll
        for (int j = 0; j < 4; j++) {
            float v = acc[i][j];
            int c = tx * 4 + j;
            if (bias) v += bias[c];
            if (ACT == 1) v = 0.5f * v * (1.f + erff(v * 0.70710678118654752f));
            po[j] = v;
        }
        *reinterpret_cast<float4*>(&C[(size_t)gr * HID + tx * 4]) = o;
    }
}

// ---------------- attention logits ----------------
__global__ __launch_bounds__(256) void alpha_kernel(const float* __restrict__ H,
                                                    const float* __restrict__ a_src,
                                                    const float* __restrict__ a_dst,
                                                    float* __restrict__ As,
                                                    float* __restrict__ Ad) {
    __shared__ float ss[HID], sd[HID];
    int tid = threadIdx.x;
    if (tid < HID) {
        ss[tid] = a_src[tid];
        sd[tid] = a_dst[tid];
    }
    __syncthreads();
    int gid = blockIdx.x * 256 + tid;
    if (gid >= N_NODES * HEADS) return;
    int n = gid >> 2;
    int head = gid & 3;
    const float* hp = &H[(size_t)n * HID + head * CH];
    const float* sp = &ss[head * CH];
    const float* dp = &sd[head * CH];
    float s = 0.f, d = 0.f;
#pragma unroll
    for (int k = 0; k < CH; k += 4) {
        float4 v = *reinterpret_cast<const float4*>(&hp[k]);
        s += v.x * sp[k] + v.y * sp[k + 1] + v.z * sp[k + 2] + v.w * sp[k + 3];
        d += v.x * dp[k] + v.y * dp[k + 1] + v.z * dp[k + 2] + v.w * dp[k + 3];
    }
    As[gid] = s;
    Ad[gid] = d;
}

// ---------------- CSR build ----------------
__global__ void count_kernel(const int* __restrict__ ei, int* __restrict__ counts) {
    int e = blockIdx.x * 256 + threadIdx.x;
    if (e < N_EDGES) atomicAdd(&counts[ei[N_EDGES + e]], 1);
}

__global__ void scan1(const int* __restrict__ counts, int* __restrict__ rowptr,
                      int* __restrict__ bsums) {
    __shared__ int sdata[256];
    int tid = threadIdx.x;
    int base = blockIdx.x * 1024 + tid * 4;
    int v[4];
#pragma unroll
    for (int i = 0; i < 4; i++) {
        int idx = base + i;
        v[i] = (idx < N_NODES) ? counts[idx] : 0;
    }
    int t = v[0] + v[1] + v[2] + v[3];
    sdata[tid] = t;
    __syncthreads();
    for (int off = 1; off < 256; off <<= 1) {
        int x = (tid >= off) ? sdata[tid - off] : 0;
        __syncthreads();
        sdata[tid] += x;
        __syncthreads();
    }
    int run = sdata[tid] - t;
#pragma unroll
    for (int i = 0; i < 4; i++) {
        int idx = base + i;
        if (idx < N_NODES) rowptr[idx] = run;
        run += v[i];
    }
    if (tid == 255) bsums[blockIdx.x] = sdata[255];
}

__global__ void scan2(int* __restrict__ bsums, int nb, int* __restrict__ total) {
    __shared__ int s[128];
    int tid = threadIdx.x;
    int v = (tid < nb) ? bsums[tid] : 0;
    s[tid] = v;
    __syncthreads();
    for (int off = 1; off < 128; off <<= 1) {
        int x = (tid >= off) ? s[tid - off] : 0;
        __syncthreads();
        s[tid] += x;
        __syncthreads();
    }
    if (tid < nb) bsums[tid] = s[tid] - v;
    if (tid == 127) *total = s[127];
}

__global__ void scan3(int* __restrict__ rowptr, const int* __restrict__ bsums,
                      int* __restrict__ pos) {
    int b = blockIdx.x;
    int base = b * 1024 + threadIdx.x * 4;
    int add = bsums[b];
#pragma unroll
    for (int i = 0; i < 4; i++) {
        int idx = base + i;
        if (idx < N_NODES) {
            int rr = rowptr[idx] + add;
            rowptr[idx] = rr;
            pos[idx] = rr;
        }
    }
}

__global__ void fill_kernel(const int* __restrict__ ei, int* __restrict__ pos,
                            int* __restrict__ csr_src) {
    int e = blockIdx.x * 256 + threadIdx.x;
    if (e < N_EDGES) {
        int s = ei[e];
        int d = ei[N_EDGES + e];
        int slot = atomicAdd(&pos[d], 1);
        csr_src[slot] = s;
    }
}

// ---------------- GAT aggregation v2: single pass (no max), unroll 4 ----------------
__global__ __launch_bounds__(256) void gat_aggregate2(
    const float* __restrict__ H, const float* __restrict__ As,
    const float* __restrict__ Ad, const int* __restrict__ rowptr,
    const int* __restrict__ csr_src, const float* __restrict__ bg,
    float* __restrict__ out) {
    int wave = threadIdx.x >> 6;
    int lane = threadIdx.x & 63;
    int dst = blockIdx.x * 4 + wave;
    if (dst >= N_NODES) return;
    int head = lane >> 4;
    const float2* H2 = reinterpret_cast<const float2*>(H);

    float ad = Ad[dst * HEADS + head];
    // self-loop
    float ex = __expf(leaky(As[dst * HEADS + head] + ad));
    float denom = ex;
    float2 hv = H2[(size_t)dst * 64 + lane];
    float acc0 = ex * hv.x, acc1 = ex * hv.y;

    int e0 = rowptr[dst], e1 = rowptr[dst + 1];
    int e = e0;
    for (; e + 4 <= e1; e += 4) {
        int s0 = csr_src[e], s1 = csr_src[e + 1];
        int s2 = csr_src[e + 2], s3 = csr_src[e + 3];
        float x0 = __expf(leaky(As[s0 * HEADS + head] + ad));
        float x1 = __expf(leaky(As[s1 * HEADS + head] + ad));
        float x2 = __expf(leaky(As[s2 * HEADS + head] + ad));
        float x3 = __expf(leaky(As[s3 * HEADS + head] + ad));
        float2 h0 = H2[(size_t)s0 * 64 + lane];
        float2 h1 = H2[(size_t)s1 * 64 + lane];
        float2 h2 = H2[(size_t)s2 * 64 + lane];
        float2 h3 = H2[(size_t)s3 * 64 + lane];
        denom += x0 + x1 + x2 + x3;
        acc0 += x0 * h0.x + x1 * h1.x + x2 * h2.x + x3 * h3.x;
        acc1 += x0 * h0.y + x1 * h1.y + x2 * h2.y + x3 * h3.y;
    }
    for (; e < e1; e++) {
        int s = csr_src[e];
        float x = __expf(leaky(As[s * HEADS + head] + ad));
        float2 h = H2[(size_t)s * 64 + lane];
        denom += x;
        acc0 += x * h.x;
        acc1 += x * h.y;
    }
    int c = lane * 2;
    float rd = 1.f / denom;
    float o0 = fmaxf(acc0 * rd + bg[c], 0.f);
    float o1 = fmaxf(acc1 * rd + bg[c + 1], 0.f);
    *reinterpret_cast<float2*>(&out[(size_t)dst * HID + c]) = make_float2(o0, o1);
}

// ---------------- global_add_pool (batch is sorted) ----------------
__global__ __launch_bounds__(128) void pool_kernel(const float* __restrict__ X,
                                                   const int* __restrict__ batch,
                                                   float* __restrict__ out) {
    int tid = threadIdx.x;
    int n0 = blockIdx.x * 512;
    int n1 = n0 + 512;
    if (n1 > N_NODES) n1 = N_NODES;
    int cur = batch[n0];
    float acc = 0.f;
    for (int n = n0; n < n1; n++) {
        int g = batch[n];
        float v = X[(size_t)n * HID + tid];
        if (g != cur) {
            atomicAdd(&out[cur * HID + tid], acc);
            acc = 0.f;
            cur = g;
        }
        acc += v;
    }
    atomicAdd(&out[cur * HID + tid], acc);
}

extern "C" void kernel_launch(void* const* d_in, const int* in_sizes, int n_in,
                              void* d_out, int out_size, void* d_ws, size_t ws_size,
                              hipStream_t stream) {
    (void)in_sizes; (void)n_in; (void)out_size; (void)ws_size;
    const float* nf    = (const float*)d_in[0];
    const int*   ei    = (const int*)d_in[1];
    const int*   batch = (const int*)d_in[2];
    const float* W1    = (const float*)d_in[3];
    const float* b1    = (const float*)d_in[4];
    const float* Wg    = (const float*)d_in[5];
    const float* a_src = (const float*)d_in[6];
    const float* a_dst = (const float*)d_in[7];
    const float* bg    = (const float*)d_in[8];
    float* out = (float*)d_out;

    char* ws = (char*)d_ws;
    size_t off = 0;
    auto alloc = [&](size_t bytes) -> char* {
        char* p = ws + off;
        off += (bytes + 255) & ~(size_t)255;
        return p;
    };
    const size_t SZX = (size_t)N_NODES * HID * sizeof(float);
    float* xA     = (float*)alloc(SZX);
    float* xB     = (float*)alloc(SZX);
    float* Hbuf   = (float*)alloc(SZX);
    float* As     = (float*)alloc((size_t)N_NODES * HEADS * sizeof(float));
    float* Ad     = (float*)alloc((size_t)N_NODES * HEADS * sizeof(float));
    int*   counts = (int*)alloc((size_t)N_NODES * sizeof(int));
    int*   rowptr = (int*)alloc((size_t)(N_NODES + 1) * sizeof(int));
    int*   pos    = (int*)alloc((size_t)N_NODES * sizeof(int));
    int*   bsums  = (int*)alloc(512);
    int*   csr    = (int*)alloc((size_t)N_EDGES * sizeof(int));
    short* WT     = (short*)alloc((size_t)HID * IN_DIM * sizeof(short));

    hipMemsetAsync(counts, 0, (size_t)N_NODES * sizeof(int), stream);
    hipMemsetAsync(out, 0, (size_t)N_GRAPHS * HID * sizeof(float), stream);

    // featurizer: x = gelu(nf @ W1 + b1)  [bf16 MFMA]
    prep_wt<<<HID, 256, 0, stream>>>(W1, WT);
    gemm1_mfma<<<(N_NODES + 63) / 64, 256, 0, stream>>>(nf, WT, b1, xA, N_NODES);

    // CSR by dst (self-loops implicit)
    count_kernel<<<N_EDGES / 256, 256, 0, stream>>>(ei, counts);
    const int NSB = (N_NODES + 1023) / 1024;  // 98
    scan1<<<NSB, 256, 0, stream>>>(counts, rowptr, bsums);
    scan2<<<1, 128, 0, stream>>>(bsums, NSB, rowptr + N_NODES);
    scan3<<<NSB, 256, 0, stream>>>(rowptr, bsums, pos);
    fill_kernel<<<N_EDGES / 256, 256, 0, stream>>>(ei, pos, csr);

    const float* x = xA;
    float* nx = xB;
    for (int l = 0; l < 2; l++) {
        gemm_act<0><<<(N_NODES + 63) / 64, 256, 0, stream>>>(x, Wg + (size_t)l * HID * HID,
                                                             nullptr, Hbuf, N_NODES, HID);
        alpha_kernel<<<(N_NODES * HEADS + 255) / 256, 256, 0, stream>>>(
            Hbuf, a_src + (size_t)l * HEADS * CH, a_dst + (size_t)l * HEADS * CH, As, Ad);
        gat_aggregate2<<<N_NODES / 4, 256, 0, stream>>>(Hbuf, As, Ad, rowptr, csr,
                                                        bg + (size_t)l * HID, nx);
        float* t = (float*)x;
        x = nx;
        nx = t;
    }
    pool_kernel<<<(N_NODES + 511) / 512, 128, 0, stream>>>(x, batch, out);
}